// Round 2
// baseline (325.122 us; speedup 1.0000x reference)
//
#include <hip/hip_runtime.h>

// Bicubic (Catmull-Rom) warp, faithful to the reference's tile/reshape quirk:
// output plane k (= b*C + c) is gathered from IMAGE plane k but warped with
// DELTA plane (k % B).  (jnp.tile on [B,H,W] gives x_map[k] = new_x[k % B],
// while the gather base uses b-major/c-minor plane order.)

__device__ __forceinline__ void cubic_coeffs(float t, float c[4]) {
    float t2 = t * t;
    float t3 = t2 * t;
    c[0] = (-t3 + 2.0f * t2 - t) * 0.5f;
    c[1] = (3.0f * t3 - 5.0f * t2 + 2.0f) * 0.5f;
    c[2] = (-3.0f * t3 + 4.0f * t2 + t) * 0.5f;
    c[3] = 1.0f - (c[0] + c[1] + c[2]);
}

__global__ __launch_bounds__(256) void warp_bicubic_kernel(
    const float* __restrict__ img,
    const float* __restrict__ dx,
    const float* __restrict__ dy,
    float* __restrict__ out,
    int B, int C, int H, int W)
{
    long long idx = (long long)blockIdx.x * blockDim.x + threadIdx.x;
    long long total = (long long)B * C * H * W;
    if (idx >= total) return;

    int hw = H * W;
    int pos = (int)(idx % hw);         // y*W + x within the plane
    int k   = (int)(idx / hw);         // output/image plane (b*C + c)
    int x = pos % W;
    int y = pos / W;
    int db = k % B;                    // delta plane per the tile quirk

    int dofs = db * hw + pos;
    float fdx = dx[dofs];
    float fdy = dy[dofs];

    // Faithful normalize -> un-normalize roundtrip (identity up to fp rounding,
    // kept so floor() flips match the reference at boundaries).
    float wm1 = (float)(W - 1);
    float hm1 = (float)(H - 1);
    float nx = 2.0f * ((float)x + fdx) / wm1 - 1.0f;
    float ny = 2.0f * ((float)y + fdy) / hm1 - 1.0f;
    float xm = (nx + 1.0f) * wm1 * 0.5f;
    float ym = (ny + 1.0f) * hm1 * 0.5f;

    float x0f = floorf(xm);
    float y0f = floorf(ym);
    float tx = xm - x0f;
    float ty = ym - y0f;

    float cx[4], cy[4];
    cubic_coeffs(tx, cx);
    cubic_coeffs(ty, cy);

    int x0 = (int)x0f;
    int y0 = (int)y0f;

    int xs[4];
    int rowoff[4];
#pragma unroll
    for (int o = 0; o < 4; ++o) {
        xs[o] = min(max(x0 - 1 + o, 0), W - 1);
        rowoff[o] = min(max(y0 - 1 + o, 0), H - 1) * W;
    }

    const float* __restrict__ chan = img + (long long)k * hw;
    float acc = 0.0f;
#pragma unroll
    for (int i = 0; i < 4; ++i) {
        const float* __restrict__ row = chan + rowoff[i];
        float v = cx[0] * row[xs[0]];
        v = fmaf(cx[1], row[xs[1]], v);
        v = fmaf(cx[2], row[xs[2]], v);
        v = fmaf(cx[3], row[xs[3]], v);
        acc = fmaf(cy[i], v, acc);
    }
    out[idx] = acc;
}

extern "C" void kernel_launch(void* const* d_in, const int* in_sizes, int n_in,
                              void* d_out, int out_size, void* d_ws, size_t ws_size,
                              hipStream_t stream) {
    const float* img = (const float*)d_in[0];
    const float* dx  = (const float*)d_in[1];
    const float* dy  = (const float*)d_in[2];
    float* out = (float*)d_out;

    const int B = 8, C = 3, H = 1024, W = 1024;
    long long total = (long long)B * C * H * W;
    int block = 256;
    int grid = (int)((total + block - 1) / block);
    warp_bicubic_kernel<<<grid, block, 0, stream>>>(img, dx, dy, out, B, C, H, W);
}

// Round 3
// 257.201 us; speedup vs baseline: 1.2641x; 1.2641x over previous
//
#include <hip/hip_runtime.h>

// Bicubic (Catmull-Rom) warp, faithful to the reference's tile/reshape quirk:
// output plane k uses IMAGE plane k warped with DELTA plane (k % B).
// Planes {db, db+B, db+2B} share delta plane db -> one thread handles all 3.
// 4-tap x-window loaded as TWO ALIGNED float4s (a=(x0-1)&~3 covers x0-1..x0+2),
// taps extracted with a branch-free 2-step conditional shift.

__device__ __forceinline__ void cubic_coeffs(float t, float c[4]) {
    float t2 = t * t;
    float t3 = t2 * t;
    c[0] = (-t3 + 2.0f * t2 - t) * 0.5f;
    c[1] = (3.0f * t3 - 5.0f * t2 + 2.0f) * 0.5f;
    c[2] = (-3.0f * t3 + 4.0f * t2 + t) * 0.5f;
    c[3] = 1.0f - (c[0] + c[1] + c[2]);
}

__global__ __launch_bounds__(256) void warp_bicubic_kernel(
    const float* __restrict__ img,
    const float* __restrict__ dx,
    const float* __restrict__ dy,
    float* __restrict__ out,
    int B, int C, int H, int W)
{
    const int x  = blockIdx.x * 64 + threadIdx.x;   // blockDim = (64,4)
    const int y  = blockIdx.y * 4 + threadIdx.y;
    const int db = blockIdx.z;                      // delta plane
    const int hw = H * W;

    const int pos  = y * W + x;
    const int dofs = db * hw + pos;
    const float fdx = dx[dofs];
    const float fdy = dy[dofs];

    // Faithful normalize -> un-normalize roundtrip (identity up to fp rounding).
    const float wm1 = (float)(W - 1);
    const float hm1 = (float)(H - 1);
    float nx = 2.0f * ((float)x + fdx) / wm1 - 1.0f;
    float ny = 2.0f * ((float)y + fdy) / hm1 - 1.0f;
    float xm = (nx + 1.0f) * wm1 * 0.5f;
    float ym = (ny + 1.0f) * hm1 * 0.5f;

    const float x0f = floorf(xm);
    const float y0f = floorf(ym);
    const float tx = xm - x0f;
    const float ty = ym - y0f;

    float cx[4], cy[4];
    cubic_coeffs(tx, cx);
    cubic_coeffs(ty, cy);

    const int x0 = (int)x0f;
    const int y0 = (int)y0f;

    int rowoff[4];
#pragma unroll
    for (int i = 0; i < 4; ++i)
        rowoff[i] = min(max(y0 - 1 + i, 0), H - 1) * W;

    const int a = (x0 - 1) & ~3;            // aligned window base
    const bool fast = (x0 >= 1) && (a <= W - 8);
    const int o = (x0 - 1) - a;             // 0..3 shift within the 8-float window
    const bool s2 = (o & 2) != 0;
    const bool s1 = (o & 1) != 0;

    float acc[3] = {0.0f, 0.0f, 0.0f};

    if (fast) {
#pragma unroll
        for (int c = 0; c < 3; ++c) {
            const float* __restrict__ chan = img + (size_t)(db + c * B) * hw;
#pragma unroll
            for (int i = 0; i < 4; ++i) {
                const float* __restrict__ p = chan + rowoff[i] + a;
                float4 f0 = *(const float4*)(p);
                float4 f1 = *(const float4*)(p + 4);
                // 2-step conditional shift: t[j] = f[o + j]
                float h0 = s2 ? f0.z : f0.x;
                float h1 = s2 ? f0.w : f0.y;
                float h2 = s2 ? f1.x : f0.z;
                float h3 = s2 ? f1.y : f0.w;
                float h4 = s2 ? f1.z : f1.x;
                float t0 = s1 ? h1 : h0;
                float t1 = s1 ? h2 : h1;
                float t2 = s1 ? h3 : h2;
                float t3 = s1 ? h4 : h3;
                float v = cx[0] * t0;
                v = fmaf(cx[1], t1, v);
                v = fmaf(cx[2], t2, v);
                v = fmaf(cx[3], t3, v);
                acc[c] = fmaf(cy[i], v, acc[c]);
            }
        }
    } else {
        int xs[4];
#pragma unroll
        for (int j = 0; j < 4; ++j)
            xs[j] = min(max(x0 - 1 + j, 0), W - 1);
#pragma unroll
        for (int c = 0; c < 3; ++c) {
            const float* __restrict__ chan = img + (size_t)(db + c * B) * hw;
#pragma unroll
            for (int i = 0; i < 4; ++i) {
                const float* __restrict__ row = chan + rowoff[i];
                float v = cx[0] * row[xs[0]];
                v = fmaf(cx[1], row[xs[1]], v);
                v = fmaf(cx[2], row[xs[2]], v);
                v = fmaf(cx[3], row[xs[3]], v);
                acc[c] = fmaf(cy[i], v, acc[c]);
            }
        }
    }

#pragma unroll
    for (int c = 0; c < 3; ++c)
        out[(size_t)(db + c * B) * hw + pos] = acc[c];
}

extern "C" void kernel_launch(void* const* d_in, const int* in_sizes, int n_in,
                              void* d_out, int out_size, void* d_ws, size_t ws_size,
                              hipStream_t stream) {
    const float* img = (const float*)d_in[0];
    const float* dx  = (const float*)d_in[1];
    const float* dy  = (const float*)d_in[2];
    float* out = (float*)d_out;

    const int B = 8, C = 3, H = 1024, W = 1024;
    dim3 block(64, 4, 1);
    dim3 grid(W / 64, H / 4, B);
    warp_bicubic_kernel<<<grid, block, 0, stream>>>(img, dx, dy, out, B, C, H, W);
}

// Round 4
// 164.372 us; speedup vs baseline: 1.9780x; 1.5647x over previous
//
#include <hip/hip_runtime.h>

// Bicubic (Catmull-Rom) warp, faithful to the reference's tile/reshape quirk:
// output plane k uses IMAGE plane k warped with DELTA plane (k % B).
//
// LDS-staged version: each 256-thread block (64x4 output tile, one delta
// plane db, all 3 channels) stages a halo window
//   rows [Y-7, Y+11] x cols [X-8, X+71]   (19 x 80, stride 84 floats)
// per channel into LDS with clamped coordinates (so border taps are
// automatically correct), using coalesced float4 loads. The 48 taps per
// thread then become ds_read_b32 with immediate offsets from a single
// per-lane base — moving the gather cost off the divergent-address TA path
// (~48 cyc/instr measured) onto the LDS pipe (~6 cyc/instr).
// Per-lane global fallback covers |delta| beyond the halo (~6 sigma, ~never).

#define ROWS 19
#define COLS 80
#define STRIDE 84   // floats; 336B = 21*16 -> rows stay 16B aligned

__device__ __forceinline__ void cubic_coeffs(float t, float c[4]) {
    float t2 = t * t;
    float t3 = t2 * t;
    c[0] = (-t3 + 2.0f * t2 - t) * 0.5f;
    c[1] = (3.0f * t3 - 5.0f * t2 + 2.0f) * 0.5f;
    c[2] = (-3.0f * t3 + 4.0f * t2 + t) * 0.5f;
    c[3] = 1.0f - (c[0] + c[1] + c[2]);
}

__global__ __launch_bounds__(256) void warp_bicubic_kernel(
    const float* __restrict__ img,
    const float* __restrict__ dx,
    const float* __restrict__ dy,
    float* __restrict__ out,
    int B, int C, int H, int W)
{
    __shared__ float lds[3][ROWS][STRIDE];   // 19152 B

    const int tx = threadIdx.x;              // 0..63
    const int ty = threadIdx.y;              // 0..3
    const int tid = ty * 64 + tx;
    const int X = blockIdx.x * 64;
    const int Y = blockIdx.y * 4;
    const int db = blockIdx.z;
    const int hw = H * W;

    // ---- stage halo window (clamped) for all 3 channels ----
    const int NF4 = 3 * ROWS * (COLS / 4);   // 1140 float4 loads
    for (int i = tid; i < NF4; i += 256) {
        int ch  = i / (ROWS * 20);
        int rem = i % (ROWS * 20);
        int r = rem / 20;
        int q = rem % 20;
        int gy  = min(max(Y - 7 + r, 0), H - 1);
        int gx0 = X - 8 + q * 4;
        const float* __restrict__ src =
            img + (size_t)(db + ch * B) * hw + (size_t)gy * W;
        float4 v;
        if (gx0 >= 0 && gx0 <= W - 4) {
            v = *(const float4*)(src + gx0);
        } else {
            v.x = src[min(max(gx0    , 0), W - 1)];
            v.y = src[min(max(gx0 + 1, 0), W - 1)];
            v.z = src[min(max(gx0 + 2, 0), W - 1)];
            v.w = src[min(max(gx0 + 3, 0), W - 1)];
        }
        *(float4*)(&lds[ch][r][q * 4]) = v;
    }
    __syncthreads();

    // ---- per-pixel coords & weights (shared by the 3 channels) ----
    const int x = X + tx;
    const int y = Y + ty;
    const int pos  = y * W + x;
    const int dofs = db * hw + pos;
    const float fdx = dx[dofs];
    const float fdy = dy[dofs];

    // Faithful normalize -> un-normalize roundtrip (identity up to fp rounding).
    const float wm1 = (float)(W - 1);
    const float hm1 = (float)(H - 1);
    float nx = 2.0f * ((float)x + fdx) / wm1 - 1.0f;
    float ny = 2.0f * ((float)y + fdy) / hm1 - 1.0f;
    float xm = (nx + 1.0f) * wm1 * 0.5f;
    float ym = (ny + 1.0f) * hm1 * 0.5f;

    const float x0f = floorf(xm);
    const float y0f = floorf(ym);
    const float tfx = xm - x0f;
    const float tfy = ym - y0f;

    float cx[4], cy[4];
    cubic_coeffs(tfx, cx);
    cubic_coeffs(tfy, cy);

    const int x0 = (int)x0f;
    const int y0 = (int)y0f;

    float acc[3] = {0.0f, 0.0f, 0.0f};

    const bool fastp = (y0 >= Y - 6) && (y0 <= Y + 9) &&
                       (x0 >= X - 7) && (x0 <= X + 69);

    if (fastp) {
        // taps: lds[ch][y0-Y+6+i][x0-X+7+j] — all imm offsets from one base
        const float* __restrict__ base = &lds[0][y0 - Y + 6][x0 - X + 7];
#pragma unroll
        for (int c = 0; c < 3; ++c) {
            const float* __restrict__ cb = base + c * (ROWS * STRIDE);
#pragma unroll
            for (int i = 0; i < 4; ++i) {
                const float* __restrict__ row = cb + i * STRIDE;
                float v = cx[0] * row[0];
                v = fmaf(cx[1], row[1], v);
                v = fmaf(cx[2], row[2], v);
                v = fmaf(cx[3], row[3], v);
                acc[c] = fmaf(cy[i], v, acc[c]);
            }
        }
    } else {
        // rare tail (|delta| ~ > 6 sigma): direct clamped global gathers
        int xs[4], rowoff[4];
#pragma unroll
        for (int o = 0; o < 4; ++o) {
            xs[o] = min(max(x0 - 1 + o, 0), W - 1);
            rowoff[o] = min(max(y0 - 1 + o, 0), H - 1) * W;
        }
#pragma unroll
        for (int c = 0; c < 3; ++c) {
            const float* __restrict__ chan = img + (size_t)(db + c * B) * hw;
#pragma unroll
            for (int i = 0; i < 4; ++i) {
                const float* __restrict__ row = chan + rowoff[i];
                float v = cx[0] * row[xs[0]];
                v = fmaf(cx[1], row[xs[1]], v);
                v = fmaf(cx[2], row[xs[2]], v);
                v = fmaf(cx[3], row[xs[3]], v);
                acc[c] = fmaf(cy[i], v, acc[c]);
            }
        }
    }

#pragma unroll
    for (int c = 0; c < 3; ++c)
        out[(size_t)(db + c * B) * hw + pos] = acc[c];
}

extern "C" void kernel_launch(void* const* d_in, const int* in_sizes, int n_in,
                              void* d_out, int out_size, void* d_ws, size_t ws_size,
                              hipStream_t stream) {
    const float* img = (const float*)d_in[0];
    const float* dx  = (const float*)d_in[1];
    const float* dy  = (const float*)d_in[2];
    float* out = (float*)d_out;

    const int B = 8, C = 3, H = 1024, W = 1024;
    dim3 block(64, 4, 1);
    dim3 grid(W / 64, H / 4, B);
    warp_bicubic_kernel<<<grid, block, 0, stream>>>(img, dx, dy, out, B, C, H, W);
}

// Round 5
// 89.365 us; speedup vs baseline: 3.6381x; 1.8393x over previous
//
#include <hip/hip_runtime.h>

// Bicubic (Catmull-Rom) warp, faithful to the reference's tile/reshape quirk:
// output plane k uses IMAGE plane k warped with DELTA plane (k % B).
//
// Channel-packed LDS version. Per 256-thread block (64x4 output tile, one
// delta plane db): stage halo rows [Y-6, Y+9] x cols [X-6, X+69] (16 x 76)
// with the 3 channels packed into one float4 cell -> each of the 16 taps is
// ONE ds_read_b128 (near-sequential lane addresses, conflict-light), instead
// of 48 jittered ds_read_b32 (measured 2.4e7 conflict cycles in round 4).
// Staging: 3 coalesced dword loads per halo position + 1 lane-sequential
// ds_write_b128 (flat position index == LDS index; incremental r,c update,
// no div/mod in the loop).
// Coordinate math: xm = x + dx directly (the reference's normalize ->
// un-normalize roundtrip is an algebraic identity; fp deviation ~1e-4 px,
// far under the 0.1 absmax threshold).
// Halo covers |delta| < 5 (P ~ 6e-7); per-lane clamped global fallback else.

#define RT   6      // top/left margin
#define ROWS 16
#define COLS 76
#define NPOS (ROWS * COLS)   // 1216

__device__ __forceinline__ void cubic_coeffs(float t, float c[4]) {
    float t2 = t * t;
    float t3 = t2 * t;
    c[0] = (-t3 + 2.0f * t2 - t) * 0.5f;
    c[1] = (3.0f * t3 - 5.0f * t2 + 2.0f) * 0.5f;
    c[2] = (-3.0f * t3 + 4.0f * t2 + t) * 0.5f;
    c[3] = 1.0f - (c[0] + c[1] + c[2]);
}

__global__ __launch_bounds__(256) void warp_bicubic_kernel(
    const float* __restrict__ img,
    const float* __restrict__ dx,
    const float* __restrict__ dy,
    float* __restrict__ out,
    int B, int C, int H, int W)
{
    __shared__ float4 lds[NPOS];   // 19456 B -> 8 blocks/CU

    const int tx = threadIdx.x;              // 0..63
    const int ty = threadIdx.y;              // 0..3
    const int tid = ty * 64 + tx;
    const int X = blockIdx.x * 64;
    const int Y = blockIdx.y * 4;
    const int db = blockIdx.z;
    const int hw = H * W;

    const float* __restrict__ ch0 = img + (size_t)db * hw;
    const float* __restrict__ ch1 = img + (size_t)(db + B) * hw;
    const float* __restrict__ ch2 = img + (size_t)(db + 2 * B) * hw;

    // ---- stage halo (clamped), channels packed into float4 cells ----
    {
        int r = tid / COLS;
        int c = tid - r * COLS;
        for (int p = tid; p < NPOS; p += 256) {
            int gy = min(max(Y - RT + r, 0), H - 1);
            int gx = min(max(X - RT + c, 0), W - 1);
            size_t off = (size_t)gy * W + gx;
            float4 v;
            v.x = ch0[off];
            v.y = ch1[off];
            v.z = ch2[off];
            v.w = 0.0f;
            lds[p] = v;                       // p == r*COLS + c (lane-sequential)
            r += 3; c += 28;                  // += 256 positions
            if (c >= COLS) { c -= COLS; r += 1; }
        }
    }
    __syncthreads();

    // ---- per-pixel coords & weights (shared by the 3 channels) ----
    const int x = X + tx;
    const int y = Y + ty;
    const int pos  = y * W + x;
    const int dofs = db * hw + pos;
    const float fdx = dx[dofs];
    const float fdy = dy[dofs];

    const float xm = (float)x + fdx;
    const float ym = (float)y + fdy;
    const float x0f = floorf(xm);
    const float y0f = floorf(ym);
    const float tfx = xm - x0f;
    const float tfy = ym - y0f;

    float cx[4], cy[4];
    cubic_coeffs(tfx, cx);
    cubic_coeffs(tfy, cy);

    const int x0 = (int)x0f;
    const int y0 = (int)y0f;

    float a0 = 0.0f, a1 = 0.0f, a2 = 0.0f;

    // leftmost tap's LDS col = x0-1-(X-RT) = x0-X+5; need [0, COLS-4]
    const unsigned ulx = (unsigned)(x0 - X + (RT - 1));
    const unsigned uly = (unsigned)(y0 - Y + (RT - 1));

    if (ulx <= (unsigned)(COLS - 4) && uly <= (unsigned)(ROWS - 4)) {
        const float4* __restrict__ base = lds + uly * COLS + ulx;
#pragma unroll
        for (int i = 0; i < 4; ++i) {
#pragma unroll
            for (int j = 0; j < 4; ++j) {
                float4 t = base[i * COLS + j];   // imm offset (i*76+j)*16
                float wij = cy[i] * cx[j];
                a0 = fmaf(wij, t.x, a0);
                a1 = fmaf(wij, t.y, a1);
                a2 = fmaf(wij, t.z, a2);
            }
        }
    } else {
        // rare tail (|delta| >= 5): direct clamped global gathers
        int xs[4], rowoff[4];
#pragma unroll
        for (int o = 0; o < 4; ++o) {
            xs[o] = min(max(x0 - 1 + o, 0), W - 1);
            rowoff[o] = min(max(y0 - 1 + o, 0), H - 1) * W;
        }
#pragma unroll
        for (int i = 0; i < 4; ++i) {
            float w0 = cy[i] * cx[0], w1 = cy[i] * cx[1];
            float w2 = cy[i] * cx[2], w3 = cy[i] * cx[3];
            const float* r0 = ch0 + rowoff[i];
            const float* r1 = ch1 + rowoff[i];
            const float* r2 = ch2 + rowoff[i];
            a0 = fmaf(w0, r0[xs[0]], a0); a0 = fmaf(w1, r0[xs[1]], a0);
            a0 = fmaf(w2, r0[xs[2]], a0); a0 = fmaf(w3, r0[xs[3]], a0);
            a1 = fmaf(w0, r1[xs[0]], a1); a1 = fmaf(w1, r1[xs[1]], a1);
            a1 = fmaf(w2, r1[xs[2]], a1); a1 = fmaf(w3, r1[xs[3]], a1);
            a2 = fmaf(w0, r2[xs[0]], a2); a2 = fmaf(w1, r2[xs[1]], a2);
            a2 = fmaf(w2, r2[xs[2]], a2); a2 = fmaf(w3, r2[xs[3]], a2);
        }
    }

    out[(size_t)db * hw + pos] = a0;
    out[(size_t)(db + B) * hw + pos] = a1;
    out[(size_t)(db + 2 * B) * hw + pos] = a2;
}

extern "C" void kernel_launch(void* const* d_in, const int* in_sizes, int n_in,
                              void* d_out, int out_size, void* d_ws, size_t ws_size,
                              hipStream_t stream) {
    const float* img = (const float*)d_in[0];
    const float* dx  = (const float*)d_in[1];
    const float* dy  = (const float*)d_in[2];
    float* out = (float*)d_out;

    const int B = 8, C = 3, H = 1024, W = 1024;
    dim3 block(64, 4, 1);
    dim3 grid(W / 64, H / 4, B);
    warp_bicubic_kernel<<<grid, block, 0, stream>>>(img, dx, dy, out, B, C, H, W);
}